// Round 17
// baseline (34.296 us; speedup 1.0000x reference)
//
#include <hip/hip_runtime.h>
#include <math.h>

#define BB 32
#define LL 512
#define DD 1024
#define TT 256
#define NK 136393              // kept (s,e) pairs per batch
#define NK_LIN 131273          // off(502)
#define S_LIN 502
#define NEG_BIG  -3.0e38f      // finite stand-in for -inf
#define NEG_MASK -1.0e30f      // finite stand-in for masked logits
#define P_TOT (BB * NK)        // 4364576 (multiple of 4)
#define SC4 (P_TOT / 4)        // 1091144
#define GEMV_BLOCKS (BB * LL / 4)            // 4096
#define D1_BLOCKS (GEMV_BLOCKS + BB)         // + 32 flag blocks
#define ROWFILL_CNT ((SC4 + 255) / 256)      // 4263
#define BCHUNKS ((NK + 255) / 256)           // 533
#define D2_BLOCKS (ROWFILL_CNT + 2 * BCHUNKS)

typedef float f4v __attribute__((ext_vector_type(4)));
typedef float f2v __attribute__((ext_vector_type(2)));

__device__ __forceinline__ int off_s(int s) {
    return (s <= S_LIN) ? s * (s + 21) / 2 : NK_LIN + (s - S_LIN) * LL;
}
__device__ __forceinline__ void invert(int k, int& s, int& e) {
    if (k >= NK_LIN) {
        const int r = k - NK_LIN;
        s = S_LIN + (r >> 9);
        e = r & 511;
    } else {
        float f = sqrtf(8.0f * (float)k + 441.0f);
        s = (int)((f - 21.0f) * 0.5f);
        if (s < 0) s = 0;
        if (s > 501) s = 501;
        while ((s + 1) * (s + 22) / 2 <= k) ++s;
        while (s * (s + 21) / 2 > k) --s;
        e = k - s * (s + 21) / 2;
    }
}

// ---- d1: [GEMV read stream | per-batch flag build] -----------------------
__global__ __launch_bounds__(256) void gemv_kernel(
    const float* __restrict__ text, const float* __restrict__ W,
    const float* __restrict__ bias, const int* __restrict__ mask,
    const int* __restrict__ tmap,
    float* __restrict__ slp, float* __restrict__ elp, float* __restrict__ mlp,
    int* __restrict__ fs, int* __restrict__ fe)
{
    const int id = blockIdx.x;
    const int t  = threadIdx.x;

    if (id >= GEMV_BLOCKS) {
        // ---- flags: batch b = id - GEMV_BLOCKS; tmap scatter + mask fold --
        const int b = id - GEMV_BLOCKS;
        __shared__ unsigned char tsl[LL], tel[LL];
        tsl[t] = 0; tsl[t + 256] = 0;
        tel[t] = 0; tel[t + 256] = 0;
        __syncthreads();
        {
            int s0 = tmap[((size_t)b * TT + t) * 2 + 0];
            int e0 = tmap[((size_t)b * TT + t) * 2 + 1] - 1;
            s0 = min(max(s0, 0), LL - 1);
            e0 = min(max(e0, 0), LL - 1);
            tsl[s0] = 1;                          // benign race: all write 1
            tel[e0] = 1;
        }
        __syncthreads();
#pragma unroll
        for (int h = 0; h < 2; ++h) {
            const int l = t + h * 256;
            const int idx = b * LL + l;
            fs[idx] = (l != 0 && tsl[l] && mask[idx] == 1) ? 1 : 0;
            fe[idx] = (l != 0 && tel[l]) ? 1 : 0;
        }
        return;
    }

    // ---- GEMV: logits = text @ W + b, wave per row (measured-best) ----
    const int wid  = t >> 6;
    const int lane = t & 63;
    const int row  = id * 4 + wid;                // row = b*L + l
    const f4v* t4 = (const f4v*)(text + (size_t)row * DD);
    const f4v* w4 = (const f4v*)W;
    float a0 = 0.f, a1 = 0.f, a2 = 0.f;
#pragma unroll
    for (int j = 0; j < 4; ++j) {
        const int fi = lane + j * 64;
        f4v v  = t4[fi];                          // coalesced 1KB/instr/wave
        f4v w0 = w4[fi * 3 + 0];                  // L1-hot
        f4v w1 = w4[fi * 3 + 1];
        f4v w2 = w4[fi * 3 + 2];
        a0 += v.x * w0.x;  a1 += v.x * w0.y;  a2 += v.x * w0.z;
        a0 += v.y * w0.w;  a1 += v.y * w1.x;  a2 += v.y * w1.y;
        a0 += v.z * w1.z;  a1 += v.z * w1.w;  a2 += v.z * w2.x;
        a0 += v.w * w2.y;  a1 += v.w * w2.z;  a2 += v.w * w2.w;
    }
#pragma unroll
    for (int o = 32; o; o >>= 1) {
        a0 += __shfl_down(a0, o);
        a1 += __shfl_down(a1, o);
        a2 += __shfl_down(a2, o);
    }
    if (lane == 0) {
        const int m = mask[row];
        slp[row] = (m == 1) ? a0 + bias[0] : NEG_MASK;
        elp[row] = (m == 1) ? a1 + bias[1] : NEG_MASK;
        mlp[row] = (m == 1) ? a2 + bias[2] : NEG_MASK;
    }
}

// ---- d2: [rowfill (scores, full lines, final values) | bounds] -----------
// rowfill: 1 quad/thread. Pure-prefix quad (~93%) = 1 cmp + const f4v store.
// Boundary quad computes <=4 tail values inline from L2-resident logits and
// flags. Every cache line written fully, exactly once -> no RMW, no WAW.
__global__ __launch_bounds__(256) void fill_kernel(
    const float* __restrict__ slp, const float* __restrict__ elp,
    const float* __restrict__ mlp, const int* __restrict__ fs,
    const int* __restrict__ fe, float* __restrict__ out)
{
    const int id = blockIdx.x;
    const int t  = threadIdx.x;

    if (id < ROWFILL_CNT) {
        const int gid = id * 256 + t;
        if (gid >= SC4) return;
        const int p4 = gid * 4;
        int b = p4 / NK;                          // magic-mul
        int k = p4 - b * NK;
        int s, e;
        invert(k, s, e);

        if (e + 3 < s) {                          // whole quad in-row prefix
            f4v neg = {NEG_BIG, NEG_BIG, NEG_BIG, NEG_BIG};
            *(f4v*)(out + p4) = neg;
            return;
        }

        float vals[4];
        int rowlen = (s <= S_LIN) ? (s + 11) : LL;
#pragma unroll
        for (int kk = 0; kk < 4; ++kk) {
            float v = NEG_BIG;
            if (e >= s && s > 0) {                // tail position, s>0
                const int base = b * LL;
                if (fs[base + s] && fe[base + e]) {
                    float w = 0.f;
                    for (int l = s; l <= e; ++l) w += mlp[base + l]; // <=11 L2
                    v = slp[base + s] + elp[base + e] + w;
                    if (v < -1.0e29f) v = NEG_BIG;  // masked -> -inf in ref
                }
            }
            vals[kk] = v;
            ++e;
            if (e >= rowlen) {                    // next row / batch wrap
                e = 0; ++s;
                if (s >= LL) { s = 0; ++b; }
                rowlen = (s <= S_LIN) ? (s + 11) : LL;
            }
        }
        f4v vv = {vals[0], vals[1], vals[2], vals[3]};
        *(f4v*)(out + p4) = vv;                   // 16B aligned (p4%4==0)
        return;
    }

    // ---- bounds: invert pattern position once, fan out to 16 batches ----
    const int q = id - ROWFILL_CNT;
    const int g = (q >= BCHUNKS) ? 1 : 0;
    const int c = q - g * BCHUNKS;
    const int p = c * 256 + t;
    if (p >= NK) return;
    int s, e;
    invert(p, s, e);
    f2v v = {(float)s, (float)e};
    f2v* bp = (f2v*)(out + (size_t)P_TOT);
#pragma unroll
    for (int j = 0; j < 16; ++j) {
        const int b = g * 16 + j;
        bp[(size_t)b * NK + p] = v;               // lane-contiguous 512B/wave
    }
}

extern "C" void kernel_launch(void* const* d_in, const int* in_sizes, int n_in,
                              void* d_out, int out_size, void* d_ws, size_t ws_size,
                              hipStream_t stream) {
    const float* text = (const float*)d_in[0];   // (B,L,D) f32
    const int*   mask = (const int*)d_in[1];     // (B,L) i32
    const int*   tmap = (const int*)d_in[2];     // (B,T,2) i32
    const float* W    = (const float*)d_in[3];   // (D,3) f32
    const float* bias = (const float*)d_in[4];   // (3,) f32
    float* out = (float*)d_out;

    float* slp = (float*)d_ws;                   // B*L each
    float* elp = slp + (size_t)BB * LL;
    float* mlp = elp + (size_t)BB * LL;
    int*   fs  = (int*)(mlp + (size_t)BB * LL);
    int*   fe  = fs + (size_t)BB * LL;

    gemv_kernel<<<D1_BLOCKS, 256, 0, stream>>>(text, W, bias, mask, tmap,
                                               slp, elp, mlp, fs, fe);
    fill_kernel<<<D2_BLOCKS, 256, 0, stream>>>(slp, elp, mlp, fs, fe, out);
}

// Round 18
// 26.683 us; speedup vs baseline: 1.2853x; 1.2853x over previous
//
#include <hip/hip_runtime.h>
#include <math.h>

#define BB 32
#define LL 512
#define DD 1024
#define TT 256
#define NK 136393              // kept (s,e) pairs per batch
#define NK_LIN 131273          // off(502)
#define S_LIN 502
#define NEG_BIG  -3.0e38f      // finite stand-in for -inf
#define NEG_MASK -1.0e30f      // finite stand-in for masked logits
#define P_TOT (BB * NK)        // 4364576 (multiple of 4)
#define SC4 (P_TOT / 4)        // 1091144
#define GEMV_BLOCKS (BB * LL / 4)            // 4096
#define TAILQ_CNT (BB * 8)                   // 256 (8 per batch, 64 rows each)
#define MEMSET_CNT ((SC4 + 255) / 256)       // 4263
#define BCHUNKS ((NK + 255) / 256)           // 533
#define D2_BLOCKS (TAILQ_CNT + MEMSET_CNT + 2 * BCHUNKS)

typedef float f4v __attribute__((ext_vector_type(4)));
typedef float f2v __attribute__((ext_vector_type(2)));

__device__ __forceinline__ int off_s(int s) {
    return (s <= S_LIN) ? s * (s + 21) / 2 : NK_LIN + (s - S_LIN) * LL;
}
__device__ __forceinline__ void invert(int k, int& s, int& e) {
    if (k >= NK_LIN) {
        const int r = k - NK_LIN;
        s = S_LIN + (r >> 9);
        e = r & 511;
    } else {
        float f = sqrtf(8.0f * (float)k + 441.0f);
        s = (int)((f - 21.0f) * 0.5f);
        if (s < 0) s = 0;
        if (s > 501) s = 501;
        while ((s + 1) * (s + 22) / 2 <= k) ++s;
        while (s * (s + 21) / 2 > k) --s;
        e = k - s * (s + 21) / 2;
    }
}

// ---- d1: PURE READ stream: logits = text @ W + b, wave per row -----------
__global__ __launch_bounds__(256) void gemv_kernel(
    const float* __restrict__ text, const float* __restrict__ W,
    const float* __restrict__ bias, const int* __restrict__ mask,
    float* __restrict__ slp, float* __restrict__ elp, float* __restrict__ mlp)
{
    const int wid  = threadIdx.x >> 6;
    const int lane = threadIdx.x & 63;
    const int row  = blockIdx.x * 4 + wid;        // row = b*L + l
    const f4v* t4 = (const f4v*)(text + (size_t)row * DD);
    const f4v* w4 = (const f4v*)W;
    float a0 = 0.f, a1 = 0.f, a2 = 0.f;
#pragma unroll
    for (int j = 0; j < 4; ++j) {
        const int fi = lane + j * 64;
        f4v v  = t4[fi];                          // coalesced 1KB/instr/wave
        f4v w0 = w4[fi * 3 + 0];                  // L1-hot
        f4v w1 = w4[fi * 3 + 1];
        f4v w2 = w4[fi * 3 + 2];
        a0 += v.x * w0.x;  a1 += v.x * w0.y;  a2 += v.x * w0.z;
        a0 += v.y * w0.w;  a1 += v.y * w1.x;  a2 += v.y * w1.y;
        a0 += v.z * w1.z;  a1 += v.z * w1.w;  a2 += v.z * w2.x;
        a0 += v.w * w2.y;  a1 += v.w * w2.z;  a2 += v.w * w2.w;
    }
#pragma unroll
    for (int o = 32; o; o >>= 1) {
        a0 += __shfl_down(a0, o);
        a1 += __shfl_down(a1, o);
        a2 += __shfl_down(a2, o);
    }
    if (lane == 0) {
        const int m = mask[row];
        slp[row] = (m == 1) ? a0 + bias[0] : NEG_MASK;
        elp[row] = (m == 1) ? a1 + bias[1] : NEG_MASK;
        mlp[row] = (m == 1) ? a2 + bias[2] : NEG_MASK;
    }
}

// ---- d2: [tailquad | memset(pure quads only) | bounds] -------------------
// Complementary full-quad partition: quad pure iff all 4 positions e<s.
// Memset writes pure quads (const f4v). Tailquad blocks (LDS-staged) write
// all non-pure quads as full f4v. Exactly-once, full lines, no stream gathers.
__global__ __launch_bounds__(256) void emit_kernel(
    const float* __restrict__ slp, const float* __restrict__ elp,
    const float* __restrict__ mlp, const int* __restrict__ mask,
    const int* __restrict__ tmap, float* __restrict__ out)
{
    const int id = blockIdx.x;
    const int t  = threadIdx.x;

    if (id < TAILQ_CNT) {
        // ======== tailquad: batch b, rows [r0, r0+64) ========
        const int b  = id >> 3;
        const int r0 = (id & 7) << 6;
        __shared__ float sl[LL], el[LL], ml[LL];
        __shared__ unsigned char fsb[LL], feb[LL];
        const int base = b * LL;
        const int i0 = t, i1 = t + 256;
        const int mk0 = mask[base + i0], mk1 = mask[base + i1];
        sl[i0] = slp[base + i0]; el[i0] = elp[base + i0]; ml[i0] = mlp[base + i0];
        sl[i1] = slp[base + i1]; el[i1] = elp[base + i1]; ml[i1] = mlp[base + i1];
        fsb[i0] = 0; fsb[i1] = 0; feb[i0] = 0; feb[i1] = 0;
        __syncthreads();
        {   // t in [0,256) == TT
            int s0 = tmap[((size_t)b * TT + t) * 2 + 0];
            int e0 = tmap[((size_t)b * TT + t) * 2 + 1] - 1;
            s0 = min(max(s0, 0), LL - 1);
            e0 = min(max(e0, 0), LL - 1);
            fsb[s0] = 1;                          // benign race: all write 1
            feb[e0] = 1;
        }
        __syncthreads();
        fsb[i0] = (i0 != 0 && fsb[i0] && mk0 == 1) ? 1 : 0;
        fsb[i1] = (fsb[i1] && mk1 == 1) ? 1 : 0;
        feb[i0] = (i0 != 0 && feb[i0]) ? 1 : 0;
        __syncthreads();

        // 64 rows x 5 quad-slots; ownership = quad's first position in row s
        for (int it = t; it < 64 * 5; it += 256) {
            const int s_loc = it / 5;
            const int slot  = it - s_loc * 5;     // 0..4
            const int s     = r0 + s_loc;
            const int offf  = b * NK + off_s(s);  // flat row start
            const int rowlen = (s <= S_LIN) ? (s + 11) : LL;
            const int p0 = ((((offf + s) >> 2) - 1 + slot) << 2);
            if (p0 < offf || p0 >= offf + rowlen) continue;   // not owner
            float vals[4];
            bool nonpure = false;
#pragma unroll
            for (int kk = 0; kk < 4; ++kk) {
                const int p = p0 + kk;
                float v = NEG_BIG;
                int rr, er;
                if (p < offf + rowlen) { rr = s;     er = p - offf; }
                else                   { rr = s + 1; er = p - offf - rowlen; }
                if (rr < LL) {
                    if (er >= rr) {               // tail position
                        nonpure = true;
                        if (fsb[rr] && feb[er]) {
                            float w = 0.f;
                            for (int l = rr; l <= er; ++l) w += ml[l];
                            v = sl[rr] + el[er] + w;
                            if (v < -1.0e29f) v = NEG_BIG;  // masked -> -inf
                        }
                    }
                } else {
                    nonpure = true;               // next batch row 0: s'=0 invalid
                }
                vals[kk] = v;
            }
            if (nonpure) {
                f4v vv = {vals[0], vals[1], vals[2], vals[3]};
                *(f4v*)(out + p0) = vv;           // full 16B line segment
            }
        }
        return;
    }

    if (id < TAILQ_CNT + MEMSET_CNT) {
        // ======== memset: write PURE quads only (all 4 positions e<s) ======
        const int gid = (id - TAILQ_CNT) * 256 + t;
        if (gid >= SC4) return;
        const int p4 = gid * 4;
        int b = p4 / NK;                          // magic-mul
        int k = p4 - b * NK;
        int s, e;
        invert(k, s, e);
        bool pure;
        if (e + 3 < s) {                          // fast path (~93%)
            pure = true;
        } else {
            pure = true;
            int ss = s, ee = e;
            int rowlen = (ss <= S_LIN) ? (ss + 11) : LL;
#pragma unroll
            for (int kk = 0; kk < 4; ++kk) {
                if (ee >= ss) { pure = false; break; }
                ++ee;
                if (ee >= rowlen) {
                    ee = 0; ++ss;
                    if (ss >= LL) ss = 0;         // next batch row 0
                    rowlen = (ss <= S_LIN) ? (ss + 11) : LL;
                }
            }
        }
        if (pure) {
            f4v neg = {NEG_BIG, NEG_BIG, NEG_BIG, NEG_BIG};
            *(f4v*)(out + p4) = neg;
        }
        return;
    }

    // ======== bounds: invert pattern position once, fan out to 16 batches ==
    const int q = id - TAILQ_CNT - MEMSET_CNT;
    const int g = (q >= BCHUNKS) ? 1 : 0;
    const int c = q - g * BCHUNKS;
    const int p = c * 256 + t;
    if (p >= NK) return;
    int s, e;
    invert(p, s, e);
    f2v v = {(float)s, (float)e};
    f2v* bp = (f2v*)(out + (size_t)P_TOT);
#pragma unroll
    for (int j = 0; j < 16; ++j) {
        const int b = g * 16 + j;
        bp[(size_t)b * NK + p] = v;               // lane-contiguous 512B/wave
    }
}

extern "C" void kernel_launch(void* const* d_in, const int* in_sizes, int n_in,
                              void* d_out, int out_size, void* d_ws, size_t ws_size,
                              hipStream_t stream) {
    const float* text = (const float*)d_in[0];   // (B,L,D) f32
    const int*   mask = (const int*)d_in[1];     // (B,L) i32
    const int*   tmap = (const int*)d_in[2];     // (B,T,2) i32
    const float* W    = (const float*)d_in[3];   // (D,3) f32
    const float* bias = (const float*)d_in[4];   // (3,) f32
    float* out = (float*)d_out;

    float* slp = (float*)d_ws;                   // B*L each
    float* elp = slp + (size_t)BB * LL;
    float* mlp = elp + (size_t)BB * LL;

    gemv_kernel<<<GEMV_BLOCKS, 256, 0, stream>>>(text, W, bias, mask,
                                                 slp, elp, mlp);
    emit_kernel<<<D2_BLOCKS, 256, 0, stream>>>(slp, elp, mlp, mask, tmap, out);
}